// Round 8
// baseline (112.530 us; speedup 1.0000x reference)
//
#include <hip/hip_runtime.h>

typedef _Float16 h8 __attribute__((ext_vector_type(8)));
typedef _Float16 h4 __attribute__((ext_vector_type(4)));
typedef float f4 __attribute__((ext_vector_type(4)));
typedef unsigned int uint32;

#define NT 7        // n-tiles: 112 output features (100 real)
#define KC 4        // k-chunks of 32: k=0..99 real, k=100 -> t, k=101 -> 1
#define HSTRIDE 104 // 52 words/row; 208 B rows -> 16B-aligned rows

// ONE WAVE = ONE TREE. 64-thread blocks, zero __syncthreads: all LDS traffic
// is intra-wave (DS pipe processes a wave's ops in program order). In-place
// comb buffer: level-d tile i reads rows 16i..16i+15, then writes 8i..8i+7;
// tile j>i reads rows >=16i+16 -> no WAR overlap.
__global__ __launch_bounds__(64, 1)
void grnn_fused(const float* __restrict__ times,
                const float* __restrict__ Qw,
                const float* __restrict__ Qb,
                const float* __restrict__ Ww,
                const float* __restrict__ Wb,
                const float* __restrict__ Pw,
                const float* __restrict__ Pb,
                float* __restrict__ out)
{
  __shared__ __align__(16) _Float16 Cs[128][HSTRIDE]; // 26624 B comb buffer
  __shared__ __align__(8)  _Float16 ts[1026];         // f16 times, heap i -> ts[1+i]
  __shared__ __align__(16) float qw_s[128];           // zero-padded
  __shared__ __align__(16) float qb_s[128];

  const int lane = threadIdx.x;        // 0..63
  const int l15  = lane & 15;
  const int kg   = lane >> 4;
  const int tree = blockIdx.x;

  // ---- stage times (f16) + Q vectors (no barrier: same-wave DS order) ----
  {
    const float* tg = times + tree * 1023;
    #pragma unroll
    for (int i = 0; i < 16; ++i) {
      const int idx = lane + 64 * i;
      if (idx < 1023) ts[1 + idx] = (_Float16)tg[idx];
    }
    if (lane == 0) ts[0] = (_Float16)0.f;
    #pragma unroll
    for (int i = 0; i < 2; ++i) {
      const int idx = lane + 64 * i;
      float qw = 0.f, qb = 0.f;
      if (idx < 100) { qw = Qw[idx]; qb = Qb[idx]; }
      qw_s[idx] = qw; qb_s[idx] = qb;
    }
  }

  // ---- persistent W fragments from global (B[k][n] = Ww[n][k]);
  //      fold rows: B[100][n] = Qw[n], B[101][n] = Qb[n] + Wb[n] ----
  h8 wf[NT][KC];
  #pragma unroll
  for (int nt = 0; nt < NT; ++nt) {
    const int r = nt * 16 + l15;           // output feature (Ww row)
    #pragma unroll
    for (int kc = 0; kc < KC; ++kc) {
      h8 v;
      #pragma unroll
      for (int j = 0; j < 8; ++j) v[j] = (_Float16)0.f;
      if (r < 100) {
        const int kb = kc * 32 + kg * 8;
        if (kc < 3) {
          const f4 w0 = *(const f4*)&Ww[r * 100 + kb];
          const f4 w1 = *(const f4*)&Ww[r * 100 + kb + 4];
          #pragma unroll
          for (int j = 0; j < 4; ++j) {
            v[j]     = (_Float16)w0[j];
            v[j + 4] = (_Float16)w1[j];
          }
        } else if (kg == 0) {              // k = 96..103
          const f4 w0 = *(const f4*)&Ww[r * 100 + 96];
          #pragma unroll
          for (int j = 0; j < 4; ++j) v[j] = (_Float16)w0[j];
          v[4] = (_Float16)Qw[r];          // k=100
          v[5] = (_Float16)(Qb[r] + Wb[r]);// k=101
        }
      }
      wf[nt][kc] = v;
    }
  }

// Swapped-operand MFMA: lane(l15,kg) reg r holds feature nt*16+kg*4+r of
// node MT*16+l15. Epilogue: ReLU, sibling pair-add (lane^1 = node^1), even
// l15 lanes store the comb row (in-place). nt==6: only kg==0 is real.
#define DO_MT(MT) do {                                                        \
    _Pragma("unroll")                                                         \
    for (int nt_ = 0; nt_ < NT; ++nt_) {                                      \
      f4 acc_ = {0.f, 0.f, 0.f, 0.f};                                         \
      _Pragma("unroll")                                                       \
      for (int kc_ = 0; kc_ < KC; ++kc_)                                      \
        acc_ = __builtin_amdgcn_mfma_f32_16x16x32_f16(wf[nt_][kc_],           \
                                                      af[kc_], acc_, 0,0,0);  \
      if (nt_ < 6 || kg == 0) {                                               \
        h4 hv_ = {(_Float16)fmaxf(acc_[0], 0.f),                              \
                  (_Float16)fmaxf(acc_[1], 0.f),                              \
                  (_Float16)fmaxf(acc_[2], 0.f),                              \
                  (_Float16)fmaxf(acc_[3], 0.f)};                             \
        uint2 u_ = __builtin_bit_cast(uint2, hv_);                            \
        u_.x = __shfl_xor(u_.x, 1, 64);                                       \
        u_.y = __shfl_xor(u_.y, 1, 64);                                       \
        hv_ = hv_ + __builtin_bit_cast(h4, u_);                               \
        if ((l15 & 1) == 0)                                                   \
          *(h4*)&Cs[(MT) * 8 + (l15 >> 1)][nt_ * 16 + kg * 4] = hv_;          \
      }                                                                       \
    }                                                                         \
  } while (0)

// Root: store h itself (no pair-add); node 0 = column l15==0 -> row 0.
#define DO_MT_ROOT() do {                                                     \
    _Pragma("unroll")                                                         \
    for (int nt_ = 0; nt_ < NT; ++nt_) {                                      \
      f4 acc_ = {0.f, 0.f, 0.f, 0.f};                                         \
      _Pragma("unroll")                                                       \
      for (int kc_ = 0; kc_ < KC; ++kc_)                                      \
        acc_ = __builtin_amdgcn_mfma_f32_16x16x32_f16(wf[nt_][kc_],           \
                                                      af[kc_], acc_, 0,0,0);  \
      if ((nt_ < 6 || kg == 0) && l15 == 0) {                                 \
        h4 hv_ = {(_Float16)fmaxf(acc_[0], 0.f),                              \
                  (_Float16)fmaxf(acc_[1], 0.f),                              \
                  (_Float16)fmaxf(acc_[2], 0.f),                              \
                  (_Float16)fmaxf(acc_[3], 0.f)};                             \
        *(h4*)&Cs[0][nt_ * 16 + kg * 4] = hv_;                                \
      }                                                                       \
    }                                                                         \
  } while (0)

// af[m=node l15][k]: k<100 -> comb row MT*16+l15; k=100 -> t(node); k=101 -> 1
#define LOAD_AFR(MT, S) do {                                                  \
    const int row_ = (MT) * 16 + l15;                                         \
    _Pragma("unroll")                                                         \
    for (int kc_ = 0; kc_ < 3; ++kc_)                                         \
      af[kc_] = *(const h8*)&Cs[row_][kc_ * 32 + kg * 8];                     \
    if (kg == 0) {                                                            \
      h4 lo_ = *(const h4*)&Cs[row_][96];                                     \
      h4 hi_ = {ts[1 + (S) + (MT) * 16 + l15], (_Float16)1.f,                 \
                (_Float16)0.f, (_Float16)0.f};                                \
      af[3] = __builtin_shufflevector(lo_, hi_, 0, 1, 2, 3, 4, 5, 6, 7);      \
    } else {                                                                  \
      _Pragma("unroll")                                                       \
      for (int j_ = 0; j_ < 8; ++j_) af[3][j_] = (_Float16)0.f;               \
    }                                                                         \
  } while (0)

  // ---- level 8 (256 nodes): leaves fused in VALU; 16 tiles, this wave ----
  #pragma unroll 1
  for (int i = 0; i < 16; ++i) {
    const int m = i * 16 + l15;
    const uint32 tp = *(const uint32*)&ts[512 + 2 * m]; // leaf pair (aligned)
    const float t0 = (float)*(const _Float16*)&tp;
    const float t1 = (float)*((const _Float16*)&tp + 1);
    h8 af[KC];
    #pragma unroll
    for (int kc = 0; kc < KC; ++kc) {
      const int kb = kc * 32 + kg * 8;
      const f4 qwa = *(const f4*)&qw_s[kb];
      const f4 qwb = *(const f4*)&qw_s[kb + 4];
      const f4 qba = *(const f4*)&qb_s[kb];
      const f4 qbb = *(const f4*)&qb_s[kb + 4];
      #pragma unroll
      for (int j = 0; j < 4; ++j) {
        float h0 = fmaxf(t0 * qwa[j] + qba[j], 0.f);
        float h1 = fmaxf(t1 * qwa[j] + qba[j], 0.f);
        af[kc][j] = (_Float16)(h0 + h1);
        float g0 = fmaxf(t0 * qwb[j] + qbb[j], 0.f);
        float g1 = fmaxf(t1 * qwb[j] + qbb[j], 0.f);
        af[kc][j + 4] = (_Float16)(g0 + g1);
      }
    }
    if (kg == 0) {                       // fold slots k=100,101
      af[3][4] = ts[1 + 255 + m];
      af[3][5] = (_Float16)1.f;
      af[3][6] = (_Float16)0.f;
      af[3][7] = (_Float16)0.f;
    }
    DO_MT(i);
  }

  // ---- levels 7..1: in-place, no barriers ----
  #pragma unroll 1
  for (int d = 7; d >= 1; --d) {
    const int s  = (1 << d) - 1;
    const int nm = (d >= 4) ? (1 << (d - 4)) : 1;
    #pragma unroll 1
    for (int i = 0; i < nm; ++i) {
      h8 af[KC];
      LOAD_AFR(i, s);
      DO_MT(i);
    }
  }

  // ---- root (d=0): read comb rows 0..15 (row 0 real), store h to row 0 ----
  {
    h8 af[KC];
    LOAD_AFR(0, 0);
    DO_MT_ROOT();
  }

  // ---- projection: out[p] = root . Pw[p] + Pb[p], p<5 (wave-wide) ----
  #pragma unroll 1
  for (int p = 0; p < 5; ++p) {
    float v = (float)Cs[0][lane] * Pw[p * 100 + lane];
    if (lane < 36) v += (float)Cs[0][64 + lane] * Pw[p * 100 + 64 + lane];
    v += __shfl_xor(v, 32, 64);
    v += __shfl_xor(v, 16, 64);
    v += __shfl_xor(v, 8, 64);
    v += __shfl_xor(v, 4, 64);
    v += __shfl_xor(v, 2, 64);
    v += __shfl_xor(v, 1, 64);
    if (lane == 0) out[tree * 5 + p] = v + Pb[p];
  }
#undef DO_MT
#undef DO_MT_ROOT
#undef LOAD_AFR
}

extern "C" void kernel_launch(void* const* d_in, const int* in_sizes, int n_in,
                              void* d_out, int out_size, void* d_ws, size_t ws_size,
                              hipStream_t stream) {
  (void)n_in; (void)out_size; (void)d_ws; (void)ws_size;
  const float* times = (const float*)d_in[0];
  const float* Qw = (const float*)d_in[1];
  const float* Qb = (const float*)d_in[2];
  const float* Ww = (const float*)d_in[3];
  const float* Wb = (const float*)d_in[4];
  const float* Pw = (const float*)d_in[5];
  const float* Pb = (const float*)d_in[6];
  float* outp = (float*)d_out;
  const int B = in_sizes[0] / 1023;   // 1024 trees -> 1024 one-wave blocks
  grnn_fused<<<dim3(B), dim3(64), 0, stream>>>(times, Qw, Qb, Ww, Wb, Pw, Pb, outp);
}

// Round 9
// 94.051 us; speedup vs baseline: 1.1965x; 1.1965x over previous
//
#include <hip/hip_runtime.h>

typedef _Float16 h8 __attribute__((ext_vector_type(8)));
typedef _Float16 h4 __attribute__((ext_vector_type(4)));
typedef _Float16 h2 __attribute__((ext_vector_type(2)));
typedef float f4 __attribute__((ext_vector_type(4)));

#define NT 7        // n-tiles: 112 output features (100 real)
#define KC 4        // k-chunks of 32: k=0..99 real, k=100 -> t, k=101 -> 1
#define HSTRIDE 104 // halves per comb row (208 B, 16B-aligned)

// ONE WAVE = ONE TREE; all trees resident; wall time == one wave's critical
// path. This version attacks the path: DPP sibling-add (no DS shuffles),
// prefetched af fragments, packed-f16 leaves, trash-block stores (no exec
// masking). In-place comb buffer WAR-safety: tile i reads rows 16i..16i+15,
// writes 8i..8i+7; prefetch of tile i+1 reads rows >= 16i+16 (level d+1
// data, already written) -> never overlaps pending writes.
__global__ __launch_bounds__(64, 1)
void grnn_fused(const float* __restrict__ times,
                const float* __restrict__ Qw,
                const float* __restrict__ Qb,
                const float* __restrict__ Ww,
                const float* __restrict__ Wb,
                const float* __restrict__ Pw,
                const float* __restrict__ Pb,
                float* __restrict__ out)
{
  __shared__ __align__(16) _Float16 Cs[128][HSTRIDE]; // 26624 B comb buffer
  __shared__ __align__(16) _Float16 trash[512];       // sink for dead lanes
  __shared__ __align__(4)  _Float16 ts_fold[512];     // heap t[0..510] as f16
  __shared__ __align__(4)  h2 tsp[256];               // leaf pairs (t[511+2m], t[512+2m])

  const int lane = threadIdx.x;        // 0..63
  const int l15  = lane & 15;
  const int kg   = lane >> 4;
  const int tree = blockIdx.x;

  // ---- stage times: fold halves (pair-packed b32 writes) + leaf pairs ----
  {
    const float* tg = times + tree * 1023;
    #pragma unroll
    for (int q = 0; q < 4; ++q) {
      const int pr = lane + 64 * q;                    // 0..255
      *(h2*)&ts_fold[2 * pr] = (h2){(_Float16)tg[2 * pr], (_Float16)tg[2 * pr + 1]};
      tsp[pr] = (h2){(_Float16)tg[511 + 2 * pr], (_Float16)tg[512 + 2 * pr]};
    }
  }

  // ---- persistent W fragments (B[k][n]=Ww[n][k]); fold rows k=100 -> Qw,
  //      k=101 -> Qb+Wb. Same regs serve as MFMA A operand (layout symmetry).
  h8 wf[NT][KC];
  #pragma unroll
  for (int nt = 0; nt < NT; ++nt) {
    const int r = nt * 16 + l15;
    #pragma unroll
    for (int kc = 0; kc < KC; ++kc) {
      h8 v;
      #pragma unroll
      for (int j = 0; j < 8; ++j) v[j] = (_Float16)0.f;
      if (r < 100) {
        const int kb = kc * 32 + kg * 8;
        if (kc < 3) {
          const f4 w0 = *(const f4*)&Ww[r * 100 + kb];
          const f4 w1 = *(const f4*)&Ww[r * 100 + kb + 4];
          #pragma unroll
          for (int j = 0; j < 4; ++j) {
            v[j]     = (_Float16)w0[j];
            v[j + 4] = (_Float16)w1[j];
          }
        } else if (kg == 0) {
          const f4 w0 = *(const f4*)&Ww[r * 100 + 96];
          #pragma unroll
          for (int j = 0; j < 4; ++j) v[j] = (_Float16)w0[j];
          v[4] = (_Float16)Qw[r];            // k=100
          v[5] = (_Float16)(Qb[r] + Wb[r]);  // k=101
        }
      }
      wf[nt][kc] = v;
    }
  }

  // ---- packed leaf Q vectors (features kb..kb+7 per lane, f16) ----
  h8 qwp[KC], qbp[KC];
  #pragma unroll
  for (int kc = 0; kc < KC; ++kc) {
    const int kb = kc * 32 + kg * 8;
    #pragma unroll
    for (int j = 0; j < 8; ++j) {
      const int ix = kb + j;
      qwp[kc][j] = (ix < 100) ? (_Float16)Qw[ix] : (_Float16)0.f;
      qbp[kc][j] = (ix < 100) ? (_Float16)Qb[ix] : (_Float16)0.f;
    }
  }

// MFMA tile + epilogue. Lane(l15,kg) reg r = feature nt*16+kg*4+r of node
// MT*16+l15. Epilogue: cvt->relu (pk_max) -> DPP quad_perm(1,0,3,2) sibling
// add (lane^1 == node^1, pure VALU) -> even-l15 lanes store comb row; odd
// lanes and nt6/kg!=0 lanes store to trash (no exec masking).
#define DO_MT(AFR, MT) do {                                                   \
    const int rw_ = (MT) * 8 + (l15 >> 1);                                    \
    _Float16* pv_ = (l15 & 1) ? &trash[lane * 4] : &Cs[rw_][kg * 4];          \
    _Float16* p6_ = kg ? &trash[lane * 4] : pv_;                              \
    _Pragma("unroll")                                                         \
    for (int nt_ = 0; nt_ < NT; ++nt_) {                                      \
      f4 acc_ = {0.f, 0.f, 0.f, 0.f};                                         \
      _Pragma("unroll")                                                       \
      for (int kc_ = 0; kc_ < KC; ++kc_)                                      \
        acc_ = __builtin_amdgcn_mfma_f32_16x16x32_f16(wf[nt_][kc_],           \
                                                      AFR[kc_], acc_, 0,0,0); \
      h2 c0_ = {(_Float16)acc_[0], (_Float16)acc_[1]};                        \
      h2 c1_ = {(_Float16)acc_[2], (_Float16)acc_[3]};                        \
      const h2 z2_ = {(_Float16)0.f, (_Float16)0.f};                          \
      c0_ = __builtin_elementwise_max(c0_, z2_);                              \
      c1_ = __builtin_elementwise_max(c1_, z2_);                              \
      int d0_ = __builtin_amdgcn_mov_dpp(__builtin_bit_cast(int, c0_),        \
                                         0xB1, 0xF, 0xF, true);               \
      int d1_ = __builtin_amdgcn_mov_dpp(__builtin_bit_cast(int, c1_),        \
                                         0xB1, 0xF, 0xF, true);               \
      c0_ = c0_ + __builtin_bit_cast(h2, d0_);                                \
      c1_ = c1_ + __builtin_bit_cast(h2, d1_);                                \
      h4 hv_ = {c0_[0], c0_[1], c1_[0], c1_[1]};                              \
      *(h4*)((nt_ == 6 ? p6_ : pv_) + nt_ * 16) = hv_;                        \
    }                                                                         \
  } while (0)

// Root: no sibling add; only l15==0 (node 0) stores, into comb row 0.
#define DO_MT_ROOT(AFR) do {                                                  \
    _Float16* pv_ = (l15 == 0) ? &Cs[0][kg * 4] : &trash[lane * 4];           \
    _Float16* p6_ = kg ? &trash[lane * 4] : pv_;                              \
    _Pragma("unroll")                                                         \
    for (int nt_ = 0; nt_ < NT; ++nt_) {                                      \
      f4 acc_ = {0.f, 0.f, 0.f, 0.f};                                         \
      _Pragma("unroll")                                                       \
      for (int kc_ = 0; kc_ < KC; ++kc_)                                      \
        acc_ = __builtin_amdgcn_mfma_f32_16x16x32_f16(wf[nt_][kc_],           \
                                                      AFR[kc_], acc_, 0,0,0); \
      h2 c0_ = {(_Float16)acc_[0], (_Float16)acc_[1]};                        \
      h2 c1_ = {(_Float16)acc_[2], (_Float16)acc_[3]};                        \
      const h2 z2_ = {(_Float16)0.f, (_Float16)0.f};                          \
      c0_ = __builtin_elementwise_max(c0_, z2_);                              \
      c1_ = __builtin_elementwise_max(c1_, z2_);                              \
      h4 hv_ = {c0_[0], c0_[1], c1_[0], c1_[1]};                              \
      *(h4*)((nt_ == 6 ? p6_ : pv_) + nt_ * 16) = hv_;                        \
    }                                                                         \
  } while (0)

// Load af for tile (MT) at level with fold base S. All lanes unconditional:
// kg!=0 lanes' af[3] is garbage but multiplies wf==0 there (harmless).
#define LOAD_AFR(AFR, MT, S) do {                                             \
    const int row_ = (MT) * 16 + l15;                                         \
    AFR[0] = *(const h8*)&Cs[row_][kg * 8];                                   \
    AFR[1] = *(const h8*)&Cs[row_][32 + kg * 8];                              \
    AFR[2] = *(const h8*)&Cs[row_][64 + kg * 8];                              \
    h4 lo_ = *(const h4*)&Cs[row_][96];                                       \
    h4 hi_ = {ts_fold[(S) + (MT) * 16 + l15], (_Float16)1.f,                  \
              (_Float16)0.f, (_Float16)0.f};                                  \
    AFR[3] = __builtin_shufflevector(lo_, hi_, 0, 1, 2, 3, 4, 5, 6, 7);       \
  } while (0)

  // ---- level 8 (256 nodes): packed-f16 leaf comb in VALU; 16 tiles ----
  const h8 z8 = {(_Float16)0.f, (_Float16)0.f, (_Float16)0.f, (_Float16)0.f,
                 (_Float16)0.f, (_Float16)0.f, (_Float16)0.f, (_Float16)0.f};
  #pragma unroll 2
  for (int i = 0; i < 16; ++i) {
    const int m = i * 16 + l15;
    const h2 tp = tsp[m];
    const _Float16 t0 = tp[0], t1 = tp[1];
    h8 afl[KC];
    #pragma unroll
    for (int kc = 0; kc < KC; ++kc) {
      h8 a = qwp[kc] * t0 + qbp[kc];
      h8 b = qwp[kc] * t1 + qbp[kc];
      a = __builtin_elementwise_max(a, z8);
      b = __builtin_elementwise_max(b, z8);
      afl[kc] = a + b;                   // leaf comb (features >=100 are 0)
    }
    afl[3][4] = ts_fold[255 + m];        // fold t (kg!=0 lanes harmless)
    afl[3][5] = (_Float16)1.f;
    DO_MT(afl, i);
  }

  // ---- levels 7,6,5 (14 tiles): early-prefetch pipeline ----
  h8 af[KC], afn[KC];
  LOAD_AFR(af, 0, 127);                  // (7,0) — leaf rows long written
  #pragma unroll 1
  for (int j = 0; j < 14; ++j) {
    const int i = j - ((j < 8) ? 0 : (j < 12) ? 8 : 12);
    if (j < 13) {
      const int j2 = j + 1;
      const int d2 = (j2 < 8) ? 7 : (j2 < 12) ? 6 : 5;
      const int i2 = j2 - ((j2 < 8) ? 0 : (j2 < 12) ? 8 : 12);
      LOAD_AFR(afn, i2, (1 << d2) - 1);  // reads never overlap pending writes
    }
    DO_MT(af, i);
    if (j == 13) LOAD_AFR(afn, 0, 15);   // (4,0): after (5,1)'s stores
    #pragma unroll
    for (int c = 0; c < KC; ++c) af[c] = afn[c];
  }

  // ---- levels 4..1: single tile each; prefetch after stores (in-order DS) ----
  #pragma unroll 1
  for (int d = 4; d >= 1; --d) {
    DO_MT(af, 0);
    LOAD_AFR(afn, 0, (1 << (d - 1)) - 1);
    #pragma unroll
    for (int c = 0; c < KC; ++c) af[c] = afn[c];
  }

  // ---- root ----
  DO_MT_ROOT(af);

  // ---- projection: out[p] = root . Pw[p] + Pb[p], p<5 (wave-wide) ----
  #pragma unroll 1
  for (int p = 0; p < 5; ++p) {
    float v = (float)Cs[0][lane] * Pw[p * 100 + lane];
    if (lane < 36) v += (float)Cs[0][64 + lane] * Pw[p * 100 + 64 + lane];
    v += __shfl_xor(v, 32, 64);
    v += __shfl_xor(v, 16, 64);
    v += __shfl_xor(v, 8, 64);
    v += __shfl_xor(v, 4, 64);
    v += __shfl_xor(v, 2, 64);
    v += __shfl_xor(v, 1, 64);
    if (lane == 0) out[tree * 5 + p] = v + Pb[p];
  }
#undef DO_MT
#undef DO_MT_ROOT
#undef LOAD_AFR
}

extern "C" void kernel_launch(void* const* d_in, const int* in_sizes, int n_in,
                              void* d_out, int out_size, void* d_ws, size_t ws_size,
                              hipStream_t stream) {
  (void)n_in; (void)out_size; (void)d_ws; (void)ws_size;
  const float* times = (const float*)d_in[0];
  const float* Qw = (const float*)d_in[1];
  const float* Qb = (const float*)d_in[2];
  const float* Ww = (const float*)d_in[3];
  const float* Wb = (const float*)d_in[4];
  const float* Pw = (const float*)d_in[5];
  const float* Pb = (const float*)d_in[6];
  float* outp = (float*)d_out;
  const int B = in_sizes[0] / 1023;   // 1024 trees -> 1024 one-wave blocks
  grnn_fused<<<dim3(B), dim3(64), 0, stream>>>(times, Qw, Qb, Ww, Wb, Pw, Pb, outp);
}